// Round 4
// baseline (143.290 us; speedup 1.0000x reference)
//
#include <hip/hip_runtime.h>
#include <hip/hip_fp16.h>
#include <cstdint>

#define N_RAND   20
#define N_GATES  28
#define E_DIM    512

struct OpsArg { int d[N_GATES]; };

// ---------- compile-time replication of np.random.RandomState(0) op list ----------
struct MT19937ce {
  uint32_t mt[624] = {};
  int mti = 0;
  constexpr void seed(uint32_t s){
    mt[0]=s;
    for(int i=1;i<624;i++) mt[i]=1812433253u*(mt[i-1]^(mt[i-1]>>30))+(uint32_t)i;
    mti=624;
  }
  constexpr uint32_t next(){
    if(mti>=624){
      for(int i=0;i<624;i++){
        uint32_t y=(mt[i]&0x80000000u)|(mt[(i+1)%624]&0x7fffffffu);
        mt[i]=mt[(i+397)%624]^(y>>1)^((y&1u)?0x9908b0dfu:0u);
      }
      mti=0;
    }
    uint32_t y=mt[mti++];
    y^=y>>11; y^=(y<<7)&0x9d2c5680u; y^=(y<<15)&0xefc60000u; y^=y>>18;
    return y;
  }
  constexpr uint32_t interval(uint32_t mx){
    if(!mx) return 0;
    uint32_t mask=mx; mask|=mask>>1; mask|=mask>>2; mask|=mask>>4; mask|=mask>>8; mask|=mask>>16;
    uint32_t v = next()&mask;
    while(v>mx) v = next()&mask;
    return v;
  }
};

constexpr OpsArg build_ops_ce(){
  MT19937ce rs; rs.seed(0);
  OpsArg o{};
  for(int i=0;i<N_RAND;i++){
    uint32_t k = rs.interval(3);
    if(k==3){
      int perm[8] = {0,1,2,3,4,5,6,7};
      for(int j=7;j>=1;j--){
        uint32_t t=rs.interval((uint32_t)j);
        int tmp=perm[j]; perm[j]=perm[t]; perm[t]=tmp;
      }
      o.d[i] = 3 | (perm[0]<<2) | (perm[1]<<5);
    } else {
      uint32_t w = rs.interval(7);
      o.d[i] = (int)k | ((int)w<<2);
    }
  }
  for(int i=0;i<8;i++) o.d[N_RAND+i] = 1 | (i<<2);
  return o;
}
inline constexpr OpsArg OPS = build_ops_ce();

// ---------- device helpers ----------
__device__ __forceinline__ float readlane_f(float v, int l){
  return __int_as_float(__builtin_amdgcn_readlane(__float_as_int(v), l));
}
template<int CTRL>
__device__ __forceinline__ float dpp_mov(float v){
  int s = __float_as_int(v);
  return __int_as_float(__builtin_amdgcn_update_dpp(s, s, CTRL, 0xF, 0xF, false));
}
// cross-lane xor<M> within 32-lane groups (M in {1,2,4,8,16})
template<int M>
__device__ __forceinline__ float xl(float v){
  if constexpr (M==1)      return dpp_mov<0xB1>(v);            // quad_perm [1,0,3,2]
  else if constexpr (M==2) return dpp_mov<0x4E>(v);            // quad_perm [2,3,0,1]
  else return __int_as_float(__builtin_amdgcn_ds_swizzle(__float_as_int(v), (M<<10)|0x1F));
}
// broadcast lane L (within each 32-lane group)
template<int L>
__device__ __forceinline__ float bcast(float v){
  return __int_as_float(__builtin_amdgcn_ds_swizzle(__float_as_int(v), L<<5));
}

typedef _Float16 v2h __attribute__((ext_vector_type(2)));
typedef _Float16 v8h __attribute__((ext_vector_type(8)));
typedef float    v4f __attribute__((ext_vector_type(4)));
union HU  { uint32_t u; v2h h; };

// ---------- fully specialized gate chain (amp idx = r*32 + l, standard bit order) ----------
template<int G>
__device__ __forceinline__ void run_gates(float (&ar)[8], float (&ai)[8],
                                          const float (&sgn)[5], int l,
                                          float cv, float sv)
{
  if constexpr (G < N_GATES){
    constexpr int dd   = OPS.d[G];
    constexpr int kind = dd & 3;
    constexpr int wa   = (dd>>2) & 7;
    constexpr int wb   = (dd>>5) & 7;
    const float gc = readlane_f(cv, G);
    const float gs = readlane_f(sv, G);

    if constexpr (kind == 3){                       // ---- CNOT c=wa t=wb ----
      if constexpr (wa < 3 && wb < 3){
        constexpr int Rc = 4>>wa, Rt = 4>>wb;
        #pragma unroll
        for (int r=0;r<8;r++){
          if ((r & Rc) && !(r & Rt)){
            float t0=ar[r]; ar[r]=ar[r|Rt]; ar[r|Rt]=t0;
            float t1=ai[r]; ai[r]=ai[r|Rt]; ai[r|Rt]=t1;
          }
        }
      } else if constexpr (wa < 3){
        constexpr int Rc = 4>>wa, Mt = 16>>(wb-3);
        #pragma unroll
        for (int r=0;r<8;r++){
          if (r & Rc){ ar[r]=xl<Mt>(ar[r]); ai[r]=xl<Mt>(ai[r]); }
        }
      } else if constexpr (wb < 3){
        constexpr int Mc = 16>>(wa-3), Rt = 4>>wb;
        const bool cb = (l & Mc) != 0;
        #pragma unroll
        for (int r=0;r<8;r++){
          if (!(r & Rt)){
            float alo=ar[r], ahi=ar[r|Rt];
            ar[r]    = cb ? ahi : alo;  ar[r|Rt] = cb ? alo : ahi;
            float blo=ai[r], bhi=ai[r|Rt];
            ai[r]    = cb ? bhi : blo;  ai[r|Rt] = cb ? blo : bhi;
          }
        }
      } else {
        constexpr int Mc = 16>>(wa-3), Mt = 16>>(wb-3);
        const bool cb = (l & Mc) != 0;
        #pragma unroll
        for (int r=0;r<8;r++){
          float pr = xl<Mt>(ar[r]), pi_ = xl<Mt>(ai[r]);
          ar[r] = cb ? pr  : ar[r];
          ai[r] = cb ? pi_ : ai[r];
        }
      }
    } else if constexpr (kind == 2){                // ---- RZ wa ----
      if constexpr (wa < 3){
        constexpr int Rb = 4>>wa;
        #pragma unroll
        for (int r=0;r<8;r++){
          const float pim = (r & Rb) ? gs : -gs;
          float nr = gc*ar[r] - pim*ai[r];
          ai[r] = gc*ai[r] + pim*ar[r];
          ar[r] = nr;
        }
      } else {
        constexpr int SI = wa-3;
        const float pim = sgn[SI]*gs;
        #pragma unroll
        for (int r=0;r<8;r++){
          float nr = gc*ar[r] - pim*ai[r];
          ai[r] = gc*ai[r] + pim*ar[r];
          ar[r] = nr;
        }
      }
    } else if constexpr (kind == 1){                // ---- RY wa ----
      if constexpr (wa < 3){
        constexpr int Rb = 4>>wa;
        #pragma unroll
        for (int r=0;r<8;r++){
          if (!(r & Rb)){
            const int h = r|Rb;
            float lr=ar[r], li=ai[r], hr=ar[h], hii=ai[h];
            ar[r]=gc*lr - gs*hr;  ai[r]=gc*li - gs*hii;
            ar[h]=gs*lr + gc*hr;  ai[h]=gs*li + gc*hii;
          }
        }
      } else {
        constexpr int M = 16>>(wa-3), SI = wa-3;
        const float sg = sgn[SI]*gs;
        #pragma unroll
        for (int r=0;r<8;r++){
          float pr = xl<M>(ar[r]), pi_ = xl<M>(ai[r]);
          ar[r] = gc*ar[r] + sg*pr;
          ai[r] = gc*ai[r] + sg*pi_;
        }
      }
    } else {                                        // ---- RX wa ----
      if constexpr (wa < 3){
        constexpr int Rb = 4>>wa;
        #pragma unroll
        for (int r=0;r<8;r++){
          if (!(r & Rb)){
            const int h = r|Rb;
            float lr=ar[r], li=ai[r], hr=ar[h], hii=ai[h];
            ar[r]=gc*lr + gs*hii;  ai[r]=gc*li - gs*hr;
            ar[h]=gc*hr + gs*li;   ai[h]=gc*hii - gs*lr;
          }
        }
      } else {
        constexpr int M = 16>>(wa-3);
        #pragma unroll
        for (int r=0;r<8;r++){
          float pr = xl<M>(ar[r]), pi_ = xl<M>(ai[r]);
          ar[r] = gc*ar[r] + gs*pi_;
          ai[r] = gc*ai[r] - gs*pr;
        }
      }
    }
    run_gates<G+1>(ar, ai, sgn, l, cv, sv);
  }
}

// ================= Pre-kernel: build U columns via the validated gate chain =================
// 16 blocks x 512 threads; each half-wave evolves one basis state b.
// Final amps (reg r, lane l) = U[j = r*32+l][b]  -> store U row-major [j][b] in f16.
__global__ __launch_bounds__(512)
void qffb_pre(const float* __restrict__ ry_theta,
              const float* __restrict__ rand_params,
              _Float16* __restrict__ Urh,     // [j=256][b=256]
              _Float16* __restrict__ Uih)     // [j=256][b=256]
{
  const int tid  = threadIdx.x;
  const int lane = tid & 63;
  const int l    = lane & 31;
  const int wave = tid >> 6;
  const int b    = blockIdx.x*16 + wave*2 + (lane>>5);   // basis index 0..255

  float th = 0.f;
  if (lane < N_GATES)
    th = (lane < N_RAND) ? rand_params[lane] : ry_theta[lane - N_RAND];
  float cv, sv;
  __sincosf(0.5f*th, &sv, &cv);

  float sgn[5];
  sgn[0] = (l&16) ? 1.f : -1.f;
  sgn[1] = (l& 8) ? 1.f : -1.f;
  sgn[2] = (l& 4) ? 1.f : -1.f;
  sgn[3] = (l& 2) ? 1.f : -1.f;
  sgn[4] = (l& 1) ? 1.f : -1.f;

  float ar[8], ai[8];
  #pragma unroll
  for (int r=0;r<8;r++){
    ar[r] = (((b>>5)==r) && ((b&31)==l)) ? 1.f : 0.f;
    ai[r] = 0.f;
  }

  run_gates<0>(ar, ai, sgn, l, cv, sv);

  #pragma unroll
  for (int r=0;r<8;r++){
    const int j = r*32 + l;
    Urh[(size_t)j*256 + b] = (_Float16)ar[r];
    Uih[(size_t)j*256 + b] = (_Float16)ai[r];
  }
}

// ================= Main kernel: psi -> S=psi@U^T (MFMA) -> P -> VALIDATED e-reduce/W1/W2 ====
// 512 thr = 8 waves, 16 tokens per block. Everything after P is verbatim R1-validated code.
#define PSTRIDE 272   // halfs: 544 B row stride
#define PFSTR   264   // floats: P row stride in the aliased Ts region
__global__ __launch_bounds__(512)
void qffb_main(const float* __restrict__ x,
               const _Float16* __restrict__ Urh,
               const _Float16* __restrict__ Uih,
               const float* __restrict__ W1,
               const float* __restrict__ b1,
               const float* __restrict__ W2,
               const float* __restrict__ b2,
               float* __restrict__ out)
{
  __shared__ _Float16 Ps[16*PSTRIDE];   // psi (f16)
  __shared__ _Float16 Hs[16][72];       // h tile (144 B stride, validated)
  __shared__ float    Ts[8][16*68];     // phase-4 epilogue; aliased as P (f32) before that
  float* Pf = &Ts[0][0];                // P[token][j], stride PFSTR (disjoint lifetime vs Ts use)

  const int tid  = threadIdx.x;
  const int lane = tid & 63;
  const int l    = lane & 31;
  const int wave = tid >> 6;
  const int rr   = lane & 15;
  const int quad = lane >> 4;
  const int trow = wave*2 + (lane>>5);          // 0..15
  const int token = blockIdx.x*16 + trow;

  // ---- phase 1: product state psi (f16), standard amp order; lane l owns amps l*8..l*8+7 ----
  // amp bit7..3 = l bit4..0 (wires 0..4), amp bits 2..0 = i (wires 5..7)
  {
    const float4 xa = *(const float4*)(x + (size_t)token*E_DIM);
    const float4 xb = *(const float4*)(x + (size_t)token*E_DIM + 4);
    float c[8], s[8];
    float xs[8] = {xa.x, xa.y, xa.z, xa.w, xb.x, xb.y, xb.z, xb.w};
    #pragma unroll
    for (int w=0; w<8; ++w) __sincosf(0.5f*xs[w], &s[w], &c[w]);
    float L = ((l&16)? s[0]:c[0]) * ((l&8)? s[1]:c[1]);
    L *= ((l&4)? s[2]:c[2]) * ((l&2)? s[3]:c[3]);
    L *= ((l&1)? s[4]:c[4]);
    const float p67[4] = {c[6]*c[7], c[6]*s[7], s[6]*c[7], s[6]*s[7]};
    v8h v;
    #pragma unroll
    for (int i=0;i<8;++i)
      v[i] = (_Float16)(L * (((i&4)? s[5]:c[5]) * p67[i&3]));
    *(v8h*)&Ps[trow*PSTRIDE + l*8] = v;
  }
  __syncthreads();

  // ---- phase 2: S[t][j] = sum_b psi[t][b] * U[j][b]  (isomorphic to validated mlp2 GEMM) ----
  v4f accr[2], acci[2];
  #pragma unroll
  for (int n=0;n<2;++n){ accr[n]=v4f{0.f,0.f,0.f,0.f}; acci[n]=v4f{0.f,0.f,0.f,0.f}; }
  for (int k=0;k<8;++k){
    const v8h a0 = *(const v8h*)&Ps[rr*PSTRIDE + k*32 + quad*8];
    #pragma unroll
    for (int n=0;n<2;++n){
      const int nt = wave*2 + n;
      const size_t boff = ((size_t)(nt*16+rr))*256 + k*32 + quad*8;
      const v8h br = *(const v8h*)(Urh + boff);
      const v8h bi = *(const v8h*)(Uih + boff);
      accr[n] = __builtin_amdgcn_mfma_f32_16x16x32_f16(a0, br, accr[n], 0,0,0);
      acci[n] = __builtin_amdgcn_mfma_f32_16x16x32_f16(a0, bi, acci[n], 0,0,0);
    }
  }
  // P store (f32) into the Pf region — nothing has read it yet, no barrier needed before.
  // D layout (validated): row(token)=quad*4+r2, col(j-in-tile)=rr
  #pragma unroll
  for (int n=0;n<2;++n){
    const int nt = wave*2 + n;
    #pragma unroll
    for (int r2=0;r2<4;++r2)
      Pf[(quad*4+r2)*PFSTR + nt*16 + rr] =
          accr[n][r2]*accr[n][r2] + acci[n][r2]*acci[n][r2];
  }
  __syncthreads();

  // ---- phase 3: VERBATIM R1-validated e-reduce + W1 + relu + Hs store ----
  float sgn[5];
  sgn[0] = (l&16) ? 1.f : -1.f;
  sgn[1] = (l& 8) ? 1.f : -1.f;
  sgn[2] = (l& 4) ? 1.f : -1.f;
  sgn[3] = (l& 2) ? 1.f : -1.f;
  sgn[4] = (l& 1) ? 1.f : -1.f;

  float p[8];
  #pragma unroll
  for (int r=0;r<8;r++) p[r] = Pf[trow*PFSTR + r*32 + l];

  const float t1a=p[0]+p[1], t1b=p[2]+p[3], t1c=p[4]+p[5], t1d=p[6]+p[7];
  const float s0a=t1a+t1b, s0b=t1c+t1d;
  float P  = s0a + s0b;
  float e0 = s0a - s0b;
  float e1 = (t1a+t1c) - (t1b+t1d);
  float e2 = (p[0]-p[1])+(p[2]-p[3])+(p[4]-p[5])+(p[6]-p[7]);
  {
    float t;
    t=xl<1>(e0); e0+=t;  t=xl<1>(e1); e1+=t;  t=xl<1>(e2); e2+=t;
    t=xl<1>(P);  P = fmaf(-sgn[4], P, t);
    t=xl<2>(e0); e0+=t;  t=xl<2>(e1); e1+=t;  t=xl<2>(e2); e2+=t;
    t=xl<2>(P);  P = fmaf(-sgn[3], P, t);
    t=xl<4>(e0); e0+=t;  t=xl<4>(e1); e1+=t;  t=xl<4>(e2); e2+=t;
    t=xl<4>(P);  P = fmaf(-sgn[2], P, t);
    t=xl<8>(e0); e0+=t;  t=xl<8>(e1); e1+=t;  t=xl<8>(e2); e2+=t;
    t=xl<8>(P);  P = fmaf(-sgn[1], P, t);
    t=xl<16>(e0); e0+=t; t=xl<16>(e1); e1+=t; t=xl<16>(e2); e2+=t;
    t=xl<16>(P); P = fmaf(-sgn[0], P, t);
  }
  const float e3 = bcast<16>(P);
  const float e4 = bcast<8>(P);
  const float e5 = bcast<4>(P);
  const float e6 = bcast<2>(P);
  const float e7 = bcast<1>(P);

  {
    const float4 wA0 = *(const float4*)(W1 + (size_t)(2*l)*8);
    const float4 wA1 = *(const float4*)(W1 + (size_t)(2*l)*8 + 4);
    const float4 wB0 = *(const float4*)(W1 + (size_t)(2*l+1)*8);
    const float4 wB1 = *(const float4*)(W1 + (size_t)(2*l+1)*8 + 4);
    const float2 bb  = *(const float2*)(b1 + 2*l);
    float h0 = bb.x + wA0.x*e0 + wA0.y*e1 + wA0.z*e2 + wA0.w*e3
                    + wA1.x*e4 + wA1.y*e5 + wA1.z*e6 + wA1.w*e7;
    float h1 = bb.y + wB0.x*e0 + wB0.y*e1 + wB0.z*e2 + wB0.w*e3
                    + wB1.x*e4 + wB1.y*e5 + wB1.z*e6 + wB1.w*e7;
    HU pk;
    pk.h = v2h{(_Float16)fmaxf(h0,0.f), (_Float16)fmaxf(h1,0.f)};
    *(uint32_t*)((char*)&Hs[trow][0] + 4*l) = pk.u;
  }
  __syncthreads();   // Hs complete; also: all Pf reads done before Ts is overwritten below

  // ---- phase 4: VERBATIM R1-validated out = H @ W2^T + b2 ----
  const int mt = blockIdx.x;
  const int ng = wave;

  const v8h a0 = *(const v8h*)&Hs[rr][quad*8];
  const v8h a1 = *(const v8h*)&Hs[rr][32 + quad*8];

  #pragma unroll
  for (int j=0;j<4;++j){
    const int e = ng*64 + j*16 + rr;
    const float4 wa = *(const float4*)(W2 + (size_t)e*64 + quad*8);
    const float4 wb = *(const float4*)(W2 + (size_t)e*64 + quad*8 + 4);
    const float4 wc = *(const float4*)(W2 + (size_t)e*64 + 32 + quad*8);
    const float4 wd = *(const float4*)(W2 + (size_t)e*64 + 32 + quad*8 + 4);
    const v8h b0 = v8h{(_Float16)wa.x,(_Float16)wa.y,(_Float16)wa.z,(_Float16)wa.w,
                      (_Float16)wb.x,(_Float16)wb.y,(_Float16)wb.z,(_Float16)wb.w};
    const v8h b1v = v8h{(_Float16)wc.x,(_Float16)wc.y,(_Float16)wc.z,(_Float16)wc.w,
                      (_Float16)wd.x,(_Float16)wd.y,(_Float16)wd.z,(_Float16)wd.w};
    v4f acc = {0.f,0.f,0.f,0.f};
    acc = __builtin_amdgcn_mfma_f32_16x16x32_f16(a0, b0, acc, 0, 0, 0);
    acc = __builtin_amdgcn_mfma_f32_16x16x32_f16(a1, b1v, acc, 0, 0, 0);
    #pragma unroll
    for (int r2=0;r2<4;r2++)
      Ts[wave][(quad*4+r2)*68 + j*16 + rr] = acc[r2];
  }

  // per-wave tile: same-wave LDS write->read is in-order (validated pattern)
  const float4 bias = *(const float4*)(b2 + ng*64 + rr*4);
  #pragma unroll
  for (int k=0;k<4;++k){
    const int row = 4*k + quad;
    float4 v = *(const float4*)&Ts[wave][row*68 + rr*4];
    v.x += bias.x; v.y += bias.y; v.z += bias.z; v.w += bias.w;
    const int t = mt*16 + row;
    *(float4*)(out + (size_t)t*E_DIM + ng*64 + rr*4) = v;
  }
}

extern "C" void kernel_launch(void* const* d_in, const int* in_sizes, int n_in,
                              void* d_out, int out_size, void* d_ws, size_t ws_size,
                              hipStream_t stream)
{
  (void)n_in; (void)out_size; (void)ws_size;
  const int ntok = in_sizes[0] / E_DIM;            // 16384
  char* ws = (char*)d_ws;
  _Float16* Urh = (_Float16*)(ws);                 // 128 KB
  _Float16* Uih = (_Float16*)(ws + 131072);        // 128 KB

  qffb_pre<<<16, 512, 0, stream>>>(
      (const float*)d_in[1],   // ry_theta
      (const float*)d_in[2],   // rand_params
      Urh, Uih);

  qffb_main<<<ntok/16, 512, 0, stream>>>(
      (const float*)d_in[0],   // x
      Urh, Uih,
      (const float*)d_in[3],   // W1
      (const float*)d_in[4],   // b1
      (const float*)d_in[5],   // W2
      (const float*)d_in[6],   // b2
      (float*)d_out);
}

// Round 6
// 121.841 us; speedup vs baseline: 1.1760x; 1.1760x over previous
//
#include <hip/hip_runtime.h>
#include <hip/hip_fp16.h>
#include <cstdint>

#define N_RAND   20
#define N_GATES  28
#define E_DIM    512

struct OpsArg { int d[N_GATES]; };

// ---------- compile-time replication of np.random.RandomState(0) op list ----------
struct MT19937ce {
  uint32_t mt[624] = {};
  int mti = 0;
  constexpr void seed(uint32_t s){
    mt[0]=s;
    for(int i=1;i<624;i++) mt[i]=1812433253u*(mt[i-1]^(mt[i-1]>>30))+(uint32_t)i;
    mti=624;
  }
  constexpr uint32_t next(){
    if(mti>=624){
      for(int i=0;i<624;i++){
        uint32_t y=(mt[i]&0x80000000u)|(mt[(i+1)%624]&0x7fffffffu);
        mt[i]=mt[(i+397)%624]^(y>>1)^((y&1u)?0x9908b0dfu:0u);
      }
      mti=0;
    }
    uint32_t y=mt[mti++];
    y^=y>>11; y^=(y<<7)&0x9d2c5680u; y^=(y<<15)&0xefc60000u; y^=y>>18;
    return y;
  }
  constexpr uint32_t interval(uint32_t mx){
    if(!mx) return 0;
    uint32_t mask=mx; mask|=mask>>1; mask|=mask>>2; mask|=mask>>4; mask|=mask>>8; mask|=mask>>16;
    uint32_t v = next()&mask;
    while(v>mx) v = next()&mask;
    return v;
  }
};

constexpr OpsArg build_ops_ce(){
  MT19937ce rs; rs.seed(0);
  OpsArg o{};
  for(int i=0;i<N_RAND;i++){
    uint32_t k = rs.interval(3);
    if(k==3){
      int perm[8] = {0,1,2,3,4,5,6,7};
      for(int j=7;j>=1;j--){
        uint32_t t=rs.interval((uint32_t)j);
        int tmp=perm[j]; perm[j]=perm[t]; perm[t]=tmp;
      }
      o.d[i] = 3 | (perm[0]<<2) | (perm[1]<<5);
    } else {
      uint32_t w = rs.interval(7);
      o.d[i] = (int)k | ((int)w<<2);
    }
  }
  for(int i=0;i<8;i++) o.d[N_RAND+i] = 1 | (i<<2);
  return o;
}
inline constexpr OpsArg OPS = build_ops_ce();

// ---------- device helpers ----------
__device__ __forceinline__ float readlane_f(float v, int l){
  return __int_as_float(__builtin_amdgcn_readlane(__float_as_int(v), l));
}
template<int CTRL>
__device__ __forceinline__ float dpp_mov(float v){
  int s = __float_as_int(v);
  return __int_as_float(__builtin_amdgcn_update_dpp(s, s, CTRL, 0xF, 0xF, false));
}
// cross-lane xor<M> within 32-lane groups (M in {1,2,4,8,16})
template<int M>
__device__ __forceinline__ float xl(float v){
  if constexpr (M==1)      return dpp_mov<0xB1>(v);            // quad_perm [1,0,3,2]
  else if constexpr (M==2) return dpp_mov<0x4E>(v);            // quad_perm [2,3,0,1]
  else return __int_as_float(__builtin_amdgcn_ds_swizzle(__float_as_int(v), (M<<10)|0x1F));
}
// broadcast lane L (within each 32-lane group)
template<int L>
__device__ __forceinline__ float bcast(float v){
  return __int_as_float(__builtin_amdgcn_ds_swizzle(__float_as_int(v), L<<5));
}

typedef _Float16 v2h __attribute__((ext_vector_type(2)));
typedef _Float16 v8h __attribute__((ext_vector_type(8)));
typedef float    v4f __attribute__((ext_vector_type(4)));
union HU  { uint32_t u; v2h h; };

// ---------- fully specialized gate chain (amp idx = r*32 + l, standard bit order) ----------
template<int G>
__device__ __forceinline__ void run_gates(float (&ar)[8], float (&ai)[8],
                                          const float (&sgn)[5], int l,
                                          float cv, float sv)
{
  if constexpr (G < N_GATES){
    constexpr int dd   = OPS.d[G];
    constexpr int kind = dd & 3;
    constexpr int wa   = (dd>>2) & 7;
    constexpr int wb   = (dd>>5) & 7;
    const float gc = readlane_f(cv, G);
    const float gs = readlane_f(sv, G);

    if constexpr (kind == 3){                       // ---- CNOT c=wa t=wb ----
      if constexpr (wa < 3 && wb < 3){
        constexpr int Rc = 4>>wa, Rt = 4>>wb;
        #pragma unroll
        for (int r=0;r<8;r++){
          if ((r & Rc) && !(r & Rt)){
            float t0=ar[r]; ar[r]=ar[r|Rt]; ar[r|Rt]=t0;
            float t1=ai[r]; ai[r]=ai[r|Rt]; ai[r|Rt]=t1;
          }
        }
      } else if constexpr (wa < 3){
        constexpr int Rc = 4>>wa, Mt = 16>>(wb-3);
        #pragma unroll
        for (int r=0;r<8;r++){
          if (r & Rc){ ar[r]=xl<Mt>(ar[r]); ai[r]=xl<Mt>(ai[r]); }
        }
      } else if constexpr (wb < 3){
        constexpr int Mc = 16>>(wa-3), Rt = 4>>wb;
        const bool cb = (l & Mc) != 0;
        #pragma unroll
        for (int r=0;r<8;r++){
          if (!(r & Rt)){
            float alo=ar[r], ahi=ar[r|Rt];
            ar[r]    = cb ? ahi : alo;  ar[r|Rt] = cb ? alo : ahi;
            float blo=ai[r], bhi=ai[r|Rt];
            ai[r]    = cb ? bhi : blo;  ai[r|Rt] = cb ? blo : bhi;
          }
        }
      } else {
        constexpr int Mc = 16>>(wa-3), Mt = 16>>(wb-3);
        const bool cb = (l & Mc) != 0;
        #pragma unroll
        for (int r=0;r<8;r++){
          float pr = xl<Mt>(ar[r]), pi_ = xl<Mt>(ai[r]);
          ar[r] = cb ? pr  : ar[r];
          ai[r] = cb ? pi_ : ai[r];
        }
      }
    } else if constexpr (kind == 2){                // ---- RZ wa ----
      if constexpr (wa < 3){
        constexpr int Rb = 4>>wa;
        #pragma unroll
        for (int r=0;r<8;r++){
          const float pim = (r & Rb) ? gs : -gs;
          float nr = gc*ar[r] - pim*ai[r];
          ai[r] = gc*ai[r] + pim*ar[r];
          ar[r] = nr;
        }
      } else {
        constexpr int SI = wa-3;
        const float pim = sgn[SI]*gs;
        #pragma unroll
        for (int r=0;r<8;r++){
          float nr = gc*ar[r] - pim*ai[r];
          ai[r] = gc*ai[r] + pim*ar[r];
          ar[r] = nr;
        }
      }
    } else if constexpr (kind == 1){                // ---- RY wa ----
      if constexpr (wa < 3){
        constexpr int Rb = 4>>wa;
        #pragma unroll
        for (int r=0;r<8;r++){
          if (!(r & Rb)){
            const int h = r|Rb;
            float lr=ar[r], li=ai[r], hr=ar[h], hii=ai[h];
            ar[r]=gc*lr - gs*hr;  ai[r]=gc*li - gs*hii;
            ar[h]=gs*lr + gc*hr;  ai[h]=gs*li + gc*hii;
          }
        }
      } else {
        constexpr int M = 16>>(wa-3), SI = wa-3;
        const float sg = sgn[SI]*gs;
        #pragma unroll
        for (int r=0;r<8;r++){
          float pr = xl<M>(ar[r]), pi_ = xl<M>(ai[r]);
          ar[r] = gc*ar[r] + sg*pr;
          ai[r] = gc*ai[r] + sg*pi_;
        }
      }
    } else {                                        // ---- RX wa ----
      if constexpr (wa < 3){
        constexpr int Rb = 4>>wa;
        #pragma unroll
        for (int r=0;r<8;r++){
          if (!(r & Rb)){
            const int h = r|Rb;
            float lr=ar[r], li=ai[r], hr=ar[h], hii=ai[h];
            ar[r]=gc*lr + gs*hii;  ai[r]=gc*li - gs*hr;
            ar[h]=gc*hr + gs*li;   ai[h]=gc*hii - gs*lr;
          }
        }
      } else {
        constexpr int M = 16>>(wa-3);
        #pragma unroll
        for (int r=0;r<8;r++){
          float pr = xl<M>(ar[r]), pi_ = xl<M>(ai[r]);
          ar[r] = gc*ar[r] + gs*pi_;
          ai[r] = gc*ai[r] - gs*pr;
        }
      }
    }
    run_gates<G+1>(ar, ai, sgn, l, cv, sv);
  }
}

// ================= Pre-kernel: build U columns, store in MFMA-FRAGMENT order ==============
// Fragment layout: F(nt,k,quad,rr,jj) = (((nt*8 + k)*4 + quad)*16 + rr)*8 + jj
// -> a wave's B-load for (nt,k) is 64 lanes x 16B contiguous (fully coalesced).
// nt = j>>4, rr = j&15 (j = row of U); k = b>>5, quad = (b>>3)&3, jj = b&7 (b = col).
__global__ __launch_bounds__(512)
void qffb_pre(const float* __restrict__ ry_theta,
              const float* __restrict__ rand_params,
              _Float16* __restrict__ Urf,
              _Float16* __restrict__ Uif)
{
  const int tid  = threadIdx.x;
  const int lane = tid & 63;
  const int l    = lane & 31;
  const int wave = tid >> 6;
  const int b    = blockIdx.x*16 + wave*2 + (lane>>5);   // basis (column) index 0..255

  float th = 0.f;
  if (lane < N_GATES)
    th = (lane < N_RAND) ? rand_params[lane] : ry_theta[lane - N_RAND];
  float cv, sv;
  __sincosf(0.5f*th, &sv, &cv);

  float sgn[5];
  sgn[0] = (l&16) ? 1.f : -1.f;
  sgn[1] = (l& 8) ? 1.f : -1.f;
  sgn[2] = (l& 4) ? 1.f : -1.f;
  sgn[3] = (l& 2) ? 1.f : -1.f;
  sgn[4] = (l& 1) ? 1.f : -1.f;

  float ar[8], ai[8];
  #pragma unroll
  for (int r=0;r<8;r++){
    ar[r] = (((b>>5)==r) && ((b&31)==l)) ? 1.f : 0.f;
    ai[r] = 0.f;
  }

  run_gates<0>(ar, ai, sgn, l, cv, sv);

  const int k  = b >> 5;
  const int qd = (b >> 3) & 3;
  const int jj = b & 7;
  #pragma unroll
  for (int r=0;r<8;r++){
    const int j   = r*32 + l;
    const int nt  = j >> 4;
    const int rr_ = j & 15;
    const size_t F = ((size_t)((nt*8 + k)*4 + qd)*16 + rr_)*8 + jj;
    Urf[F] = (_Float16)ar[r];
    Uif[F] = (_Float16)ai[r];
  }
}

// ================= Main kernel (R4 skeleton): 16 tokens/block, single m-tile ==============
#define PSTRIDE 272   // halfs: 544 B row stride
#define PFSTR   264   // floats: P row stride in the aliased Ts region
__global__ __launch_bounds__(512)
void qffb_main(const float* __restrict__ x,
               const _Float16* __restrict__ Urf,
               const _Float16* __restrict__ Uif,
               const float* __restrict__ W1,
               const float* __restrict__ b1,
               const float* __restrict__ W2,
               const float* __restrict__ b2,
               float* __restrict__ out)
{
  __shared__ _Float16 Ps[16*PSTRIDE];   // psi (f16)
  __shared__ _Float16 Hs[16][72];       // h tile (144 B stride, validated)
  __shared__ float    Ts[8][16*68];     // phase-4 epilogue; aliased as P (f32) before that
  float* Pf = &Ts[0][0];                // P[token][j], stride PFSTR (disjoint lifetime vs Ts use)

  const int tid  = threadIdx.x;
  const int lane = tid & 63;
  const int l    = lane & 31;
  const int wave = tid >> 6;
  const int rr   = lane & 15;
  const int quad = lane >> 4;
  const int trow = wave*2 + (lane>>5);          // 0..15
  const int token = blockIdx.x*16 + trow;

  // ---- phase 1: product state psi (f16), standard amp order; lane l owns amps l*8..l*8+7 ----
  {
    const float4 xa = *(const float4*)(x + (size_t)token*E_DIM);
    const float4 xb = *(const float4*)(x + (size_t)token*E_DIM + 4);
    float c[8], s[8];
    float xs[8] = {xa.x, xa.y, xa.z, xa.w, xb.x, xb.y, xb.z, xb.w};
    #pragma unroll
    for (int w=0; w<8; ++w) __sincosf(0.5f*xs[w], &s[w], &c[w]);
    float L = ((l&16)? s[0]:c[0]) * ((l&8)? s[1]:c[1]);
    L *= ((l&4)? s[2]:c[2]) * ((l&2)? s[3]:c[3]);
    L *= ((l&1)? s[4]:c[4]);
    const float p67[4] = {c[6]*c[7], c[6]*s[7], s[6]*c[7], s[6]*s[7]};
    v8h v;
    #pragma unroll
    for (int i=0;i<8;++i)
      v[i] = (_Float16)(L * (((i&4)? s[5]:c[5]) * p67[i&3]));
    *(v8h*)&Ps[trow*PSTRIDE + l*8] = v;
  }
  __syncthreads();

  // ---- phase 2: S = psi @ U^T (K=256), fragment-ordered U, unrolled + depth-1 prefetch ----
  v4f accr[2], acci[2];
  #pragma unroll
  for (int n=0;n<2;++n){ accr[n]=v4f{0.f,0.f,0.f,0.f}; acci[n]=v4f{0.f,0.f,0.f,0.f}; }

  const size_t ub0 = ((size_t)((wave*2+0)*32 + quad)*16 + rr)*8;   // F(nt0, k=0, quad, rr, 0)
  const size_t ub1 = ((size_t)((wave*2+1)*32 + quad)*16 + rr)*8;   // F(nt1, k=0, quad, rr, 0)

  v8h br0 = *(const v8h*)(Urf + ub0);
  v8h bi0 = *(const v8h*)(Uif + ub0);
  v8h br1 = *(const v8h*)(Urf + ub1);
  v8h bi1 = *(const v8h*)(Uif + ub1);

  #pragma unroll
  for (int k=0;k<8;++k){
    v8h nbr0, nbi0, nbr1, nbi1;
    if (k < 7){
      const size_t o = (size_t)(k+1)*512;      // k-step = 4*16*8 halfs
      nbr0 = *(const v8h*)(Urf + ub0 + o);
      nbi0 = *(const v8h*)(Uif + ub0 + o);
      nbr1 = *(const v8h*)(Urf + ub1 + o);
      nbi1 = *(const v8h*)(Uif + ub1 + o);
    }
    const v8h a0 = *(const v8h*)&Ps[rr*PSTRIDE + k*32 + quad*8];
    accr[0] = __builtin_amdgcn_mfma_f32_16x16x32_f16(a0, br0, accr[0], 0,0,0);
    acci[0] = __builtin_amdgcn_mfma_f32_16x16x32_f16(a0, bi0, acci[0], 0,0,0);
    accr[1] = __builtin_amdgcn_mfma_f32_16x16x32_f16(a0, br1, accr[1], 0,0,0);
    acci[1] = __builtin_amdgcn_mfma_f32_16x16x32_f16(a0, bi1, acci[1], 0,0,0);
    if (k < 7){ br0=nbr0; bi0=nbi0; br1=nbr1; bi1=nbi1; }
  }

  // P store (f32). D layout (validated): row(token)=quad*4+r2, col(j-in-tile)=rr
  #pragma unroll
  for (int n=0;n<2;++n){
    const int nt = wave*2 + n;
    #pragma unroll
    for (int r2=0;r2<4;++r2)
      Pf[(quad*4+r2)*PFSTR + nt*16 + rr] =
          accr[n][r2]*accr[n][r2] + acci[n][r2]*acci[n][r2];
  }
  __syncthreads();

  // ---- phase 3: VERBATIM R4-validated e-reduce + W1 + relu + Hs store ----
  float sgn[5];
  sgn[0] = (l&16) ? 1.f : -1.f;
  sgn[1] = (l& 8) ? 1.f : -1.f;
  sgn[2] = (l& 4) ? 1.f : -1.f;
  sgn[3] = (l& 2) ? 1.f : -1.f;
  sgn[4] = (l& 1) ? 1.f : -1.f;

  float p[8];
  #pragma unroll
  for (int r=0;r<8;r++) p[r] = Pf[trow*PFSTR + r*32 + l];

  const float t1a=p[0]+p[1], t1b=p[2]+p[3], t1c=p[4]+p[5], t1d=p[6]+p[7];
  const float s0a=t1a+t1b, s0b=t1c+t1d;
  float P  = s0a + s0b;
  float e0 = s0a - s0b;
  float e1 = (t1a+t1c) - (t1b+t1d);
  float e2 = (p[0]-p[1])+(p[2]-p[3])+(p[4]-p[5])+(p[6]-p[7]);
  {
    float t;
    t=xl<1>(e0); e0+=t;  t=xl<1>(e1); e1+=t;  t=xl<1>(e2); e2+=t;
    t=xl<1>(P);  P = fmaf(-sgn[4], P, t);
    t=xl<2>(e0); e0+=t;  t=xl<2>(e1); e1+=t;  t=xl<2>(e2); e2+=t;
    t=xl<2>(P);  P = fmaf(-sgn[3], P, t);
    t=xl<4>(e0); e0+=t;  t=xl<4>(e1); e1+=t;  t=xl<4>(e2); e2+=t;
    t=xl<4>(P);  P = fmaf(-sgn[2], P, t);
    t=xl<8>(e0); e0+=t;  t=xl<8>(e1); e1+=t;  t=xl<8>(e2); e2+=t;
    t=xl<8>(P);  P = fmaf(-sgn[1], P, t);
    t=xl<16>(e0); e0+=t; t=xl<16>(e1); e1+=t; t=xl<16>(e2); e2+=t;
    t=xl<16>(P); P = fmaf(-sgn[0], P, t);
  }
  const float e3 = bcast<16>(P);
  const float e4 = bcast<8>(P);
  const float e5 = bcast<4>(P);
  const float e6 = bcast<2>(P);
  const float e7 = bcast<1>(P);

  {
    const float4 wA0 = *(const float4*)(W1 + (size_t)(2*l)*8);
    const float4 wA1 = *(const float4*)(W1 + (size_t)(2*l)*8 + 4);
    const float4 wB0 = *(const float4*)(W1 + (size_t)(2*l+1)*8);
    const float4 wB1 = *(const float4*)(W1 + (size_t)(2*l+1)*8 + 4);
    const float2 bb  = *(const float2*)(b1 + 2*l);
    float h0 = bb.x + wA0.x*e0 + wA0.y*e1 + wA0.z*e2 + wA0.w*e3
                    + wA1.x*e4 + wA1.y*e5 + wA1.z*e6 + wA1.w*e7;
    float h1 = bb.y + wB0.x*e0 + wB0.y*e1 + wB0.z*e2 + wB0.w*e3
                    + wB1.x*e4 + wB1.y*e5 + wB1.z*e6 + wB1.w*e7;
    HU pk;
    pk.h = v2h{(_Float16)fmaxf(h0,0.f), (_Float16)fmaxf(h1,0.f)};
    *(uint32_t*)((char*)&Hs[trow][0] + 4*l) = pk.u;
  }
  __syncthreads();   // Hs complete; also: all Pf reads done before Ts is overwritten below

  // ---- phase 4: VERBATIM R4-validated out = H @ W2^T + b2 ----
  const int mt = blockIdx.x;
  const int ng = wave;

  const v8h a0 = *(const v8h*)&Hs[rr][quad*8];
  const v8h a1 = *(const v8h*)&Hs[rr][32 + quad*8];

  #pragma unroll
  for (int j=0;j<4;++j){
    const int e = ng*64 + j*16 + rr;
    const float4 wa = *(const float4*)(W2 + (size_t)e*64 + quad*8);
    const float4 wb = *(const float4*)(W2 + (size_t)e*64 + quad*8 + 4);
    const float4 wc = *(const float4*)(W2 + (size_t)e*64 + 32 + quad*8);
    const float4 wd = *(const float4*)(W2 + (size_t)e*64 + 32 + quad*8 + 4);
    const v8h b0 = v8h{(_Float16)wa.x,(_Float16)wa.y,(_Float16)wa.z,(_Float16)wa.w,
                      (_Float16)wb.x,(_Float16)wb.y,(_Float16)wb.z,(_Float16)wb.w};
    const v8h b1v = v8h{(_Float16)wc.x,(_Float16)wc.y,(_Float16)wc.z,(_Float16)wc.w,
                      (_Float16)wd.x,(_Float16)wd.y,(_Float16)wd.z,(_Float16)wd.w};
    v4f acc = {0.f,0.f,0.f,0.f};
    acc = __builtin_amdgcn_mfma_f32_16x16x32_f16(a0, b0, acc, 0, 0, 0);
    acc = __builtin_amdgcn_mfma_f32_16x16x32_f16(a1, b1v, acc, 0, 0, 0);
    #pragma unroll
    for (int r2=0;r2<4;r2++)
      Ts[wave][(quad*4+r2)*68 + j*16 + rr] = acc[r2];
  }

  // per-wave tile: same-wave LDS write->read is in-order (validated pattern)
  const float4 bias = *(const float4*)(b2 + ng*64 + rr*4);
  #pragma unroll
  for (int k=0;k<4;++k){
    const int row = 4*k + quad;
    float4 v = *(const float4*)&Ts[wave][row*68 + rr*4];
    v.x += bias.x; v.y += bias.y; v.z += bias.z; v.w += bias.w;
    const int t = mt*16 + row;
    *(float4*)(out + (size_t)t*E_DIM + ng*64 + rr*4) = v;
  }
}

extern "C" void kernel_launch(void* const* d_in, const int* in_sizes, int n_in,
                              void* d_out, int out_size, void* d_ws, size_t ws_size,
                              hipStream_t stream)
{
  (void)n_in; (void)out_size; (void)ws_size;
  const int ntok = in_sizes[0] / E_DIM;            // 16384
  char* ws = (char*)d_ws;
  _Float16* Urf = (_Float16*)(ws);                 // 128 KB (fragment layout)
  _Float16* Uif = (_Float16*)(ws + 131072);        // 128 KB

  qffb_pre<<<16, 512, 0, stream>>>(
      (const float*)d_in[1],   // ry_theta
      (const float*)d_in[2],   // rand_params
      Urf, Uif);

  qffb_main<<<ntok/16, 512, 0, stream>>>(
      (const float*)d_in[0],   // x
      Urf, Uif,
      (const float*)d_in[3],   // W1
      (const float*)d_in[4],   // b1
      (const float*)d_in[5],   // W2
      (const float*)d_in[6],   // b2
      (float*)d_out);
}

// Round 7
// 109.275 us; speedup vs baseline: 1.3113x; 1.1150x over previous
//
#include <hip/hip_runtime.h>
#include <hip/hip_fp16.h>
#include <cstdint>

#define N_RAND   20
#define N_GATES  28
#define E_DIM    512
#define TPB_TILES 4   // token-tiles (16 tokens) per block

struct OpsArg { int d[N_GATES]; };

// ---------- compile-time replication of np.random.RandomState(0) op list ----------
struct MT19937ce {
  uint32_t mt[624] = {};
  int mti = 0;
  constexpr void seed(uint32_t s){
    mt[0]=s;
    for(int i=1;i<624;i++) mt[i]=1812433253u*(mt[i-1]^(mt[i-1]>>30))+(uint32_t)i;
    mti=624;
  }
  constexpr uint32_t next(){
    if(mti>=624){
      for(int i=0;i<624;i++){
        uint32_t y=(mt[i]&0x80000000u)|(mt[(i+1)%624]&0x7fffffffu);
        mt[i]=mt[(i+397)%624]^(y>>1)^((y&1u)?0x9908b0dfu:0u);
      }
      mti=0;
    }
    uint32_t y=mt[mti++];
    y^=y>>11; y^=(y<<7)&0x9d2c5680u; y^=(y<<15)&0xefc60000u; y^=y>>18;
    return y;
  }
  constexpr uint32_t interval(uint32_t mx){
    if(!mx) return 0;
    uint32_t mask=mx; mask|=mask>>1; mask|=mask>>2; mask|=mask>>4; mask|=mask>>8; mask|=mask>>16;
    uint32_t v = next()&mask;
    while(v>mx) v = next()&mask;
    return v;
  }
};

constexpr OpsArg build_ops_ce(){
  MT19937ce rs; rs.seed(0);
  OpsArg o{};
  for(int i=0;i<N_RAND;i++){
    uint32_t k = rs.interval(3);
    if(k==3){
      int perm[8] = {0,1,2,3,4,5,6,7};
      for(int j=7;j>=1;j--){
        uint32_t t=rs.interval((uint32_t)j);
        int tmp=perm[j]; perm[j]=perm[t]; perm[t]=tmp;
      }
      o.d[i] = 3 | (perm[0]<<2) | (perm[1]<<5);
    } else {
      uint32_t w = rs.interval(7);
      o.d[i] = (int)k | ((int)w<<2);
    }
  }
  for(int i=0;i<8;i++) o.d[N_RAND+i] = 1 | (i<<2);
  return o;
}
inline constexpr OpsArg OPS = build_ops_ce();

// ---------- device helpers ----------
__device__ __forceinline__ float readlane_f(float v, int l){
  return __int_as_float(__builtin_amdgcn_readlane(__float_as_int(v), l));
}
template<int CTRL>
__device__ __forceinline__ float dpp_mov(float v){
  int s = __float_as_int(v);
  return __int_as_float(__builtin_amdgcn_update_dpp(s, s, CTRL, 0xF, 0xF, false));
}
// cross-lane xor<M> within 32-lane groups (M in {1,2,4,8,16})
template<int M>
__device__ __forceinline__ float xl(float v){
  if constexpr (M==1)      return dpp_mov<0xB1>(v);            // quad_perm [1,0,3,2]
  else if constexpr (M==2) return dpp_mov<0x4E>(v);            // quad_perm [2,3,0,1]
  else return __int_as_float(__builtin_amdgcn_ds_swizzle(__float_as_int(v), (M<<10)|0x1F));
}
// broadcast lane L (within each 32-lane group)
template<int L>
__device__ __forceinline__ float bcast(float v){
  return __int_as_float(__builtin_amdgcn_ds_swizzle(__float_as_int(v), L<<5));
}

typedef _Float16 v2h __attribute__((ext_vector_type(2)));
typedef _Float16 v8h __attribute__((ext_vector_type(8)));
typedef float    v4f __attribute__((ext_vector_type(4)));
union HU  { uint32_t u; v2h h; };

// ---------- fully specialized gate chain (amp idx = r*32 + l, standard bit order) ----------
template<int G>
__device__ __forceinline__ void run_gates(float (&ar)[8], float (&ai)[8],
                                          const float (&sgn)[5], int l,
                                          float cv, float sv)
{
  if constexpr (G < N_GATES){
    constexpr int dd   = OPS.d[G];
    constexpr int kind = dd & 3;
    constexpr int wa   = (dd>>2) & 7;
    constexpr int wb   = (dd>>5) & 7;
    const float gc = readlane_f(cv, G);
    const float gs = readlane_f(sv, G);

    if constexpr (kind == 3){                       // ---- CNOT c=wa t=wb ----
      if constexpr (wa < 3 && wb < 3){
        constexpr int Rc = 4>>wa, Rt = 4>>wb;
        #pragma unroll
        for (int r=0;r<8;r++){
          if ((r & Rc) && !(r & Rt)){
            float t0=ar[r]; ar[r]=ar[r|Rt]; ar[r|Rt]=t0;
            float t1=ai[r]; ai[r]=ai[r|Rt]; ai[r|Rt]=t1;
          }
        }
      } else if constexpr (wa < 3){
        constexpr int Rc = 4>>wa, Mt = 16>>(wb-3);
        #pragma unroll
        for (int r=0;r<8;r++){
          if (r & Rc){ ar[r]=xl<Mt>(ar[r]); ai[r]=xl<Mt>(ai[r]); }
        }
      } else if constexpr (wb < 3){
        constexpr int Mc = 16>>(wa-3), Rt = 4>>wb;
        const bool cb = (l & Mc) != 0;
        #pragma unroll
        for (int r=0;r<8;r++){
          if (!(r & Rt)){
            float alo=ar[r], ahi=ar[r|Rt];
            ar[r]    = cb ? ahi : alo;  ar[r|Rt] = cb ? alo : ahi;
            float blo=ai[r], bhi=ai[r|Rt];
            ai[r]    = cb ? bhi : blo;  ai[r|Rt] = cb ? blo : bhi;
          }
        }
      } else {
        constexpr int Mc = 16>>(wa-3), Mt = 16>>(wb-3);
        const bool cb = (l & Mc) != 0;
        #pragma unroll
        for (int r=0;r<8;r++){
          float pr = xl<Mt>(ar[r]), pi_ = xl<Mt>(ai[r]);
          ar[r] = cb ? pr  : ar[r];
          ai[r] = cb ? pi_ : ai[r];
        }
      }
    } else if constexpr (kind == 2){                // ---- RZ wa ----
      if constexpr (wa < 3){
        constexpr int Rb = 4>>wa;
        #pragma unroll
        for (int r=0;r<8;r++){
          const float pim = (r & Rb) ? gs : -gs;
          float nr = gc*ar[r] - pim*ai[r];
          ai[r] = gc*ai[r] + pim*ar[r];
          ar[r] = nr;
        }
      } else {
        constexpr int SI = wa-3;
        const float pim = sgn[SI]*gs;
        #pragma unroll
        for (int r=0;r<8;r++){
          float nr = gc*ar[r] - pim*ai[r];
          ai[r] = gc*ai[r] + pim*ar[r];
          ar[r] = nr;
        }
      }
    } else if constexpr (kind == 1){                // ---- RY wa ----
      if constexpr (wa < 3){
        constexpr int Rb = 4>>wa;
        #pragma unroll
        for (int r=0;r<8;r++){
          if (!(r & Rb)){
            const int h = r|Rb;
            float lr=ar[r], li=ai[r], hr=ar[h], hii=ai[h];
            ar[r]=gc*lr - gs*hr;  ai[r]=gc*li - gs*hii;
            ar[h]=gs*lr + gc*hr;  ai[h]=gs*li + gc*hii;
          }
        }
      } else {
        constexpr int M = 16>>(wa-3), SI = wa-3;
        const float sg = sgn[SI]*gs;
        #pragma unroll
        for (int r=0;r<8;r++){
          float pr = xl<M>(ar[r]), pi_ = xl<M>(ai[r]);
          ar[r] = gc*ar[r] + sg*pr;
          ai[r] = gc*ai[r] + sg*pi_;
        }
      }
    } else {                                        // ---- RX wa ----
      if constexpr (wa < 3){
        constexpr int Rb = 4>>wa;
        #pragma unroll
        for (int r=0;r<8;r++){
          if (!(r & Rb)){
            const int h = r|Rb;
            float lr=ar[r], li=ai[r], hr=ar[h], hii=ai[h];
            ar[r]=gc*lr + gs*hii;  ai[r]=gc*li - gs*hr;
            ar[h]=gc*hr + gs*li;   ai[h]=gc*hii - gs*lr;
          }
        }
      } else {
        constexpr int M = 16>>(wa-3);
        #pragma unroll
        for (int r=0;r<8;r++){
          float pr = xl<M>(ar[r]), pi_ = xl<M>(ai[r]);
          ar[r] = gc*ar[r] + gs*pi_;
          ai[r] = gc*ai[r] - gs*pr;
        }
      }
    }
    run_gates<G+1>(ar, ai, sgn, l, cv, sv);
  }
}

// ================= Pre-kernel: build U columns, store in MFMA-FRAGMENT order ==============
// Fragment layout: F(nt,k,quad,rr,jj) = (((nt*8 + k)*4 + quad)*16 + rr)*8 + jj
// nt = j>>4, rr = j&15 (j = row of U); k = b>>5, quad = (b>>3)&3, jj = b&7 (b = col).
__global__ __launch_bounds__(512)
void qffb_pre(const float* __restrict__ ry_theta,
              const float* __restrict__ rand_params,
              _Float16* __restrict__ Urf,
              _Float16* __restrict__ Uif)
{
  const int tid  = threadIdx.x;
  const int lane = tid & 63;
  const int l    = lane & 31;
  const int wave = tid >> 6;
  const int b    = blockIdx.x*16 + wave*2 + (lane>>5);   // basis (column) index 0..255

  float th = 0.f;
  if (lane < N_GATES)
    th = (lane < N_RAND) ? rand_params[lane] : ry_theta[lane - N_RAND];
  float cv, sv;
  __sincosf(0.5f*th, &sv, &cv);

  float sgn[5];
  sgn[0] = (l&16) ? 1.f : -1.f;
  sgn[1] = (l& 8) ? 1.f : -1.f;
  sgn[2] = (l& 4) ? 1.f : -1.f;
  sgn[3] = (l& 2) ? 1.f : -1.f;
  sgn[4] = (l& 1) ? 1.f : -1.f;

  float ar[8], ai[8];
  #pragma unroll
  for (int r=0;r<8;r++){
    ar[r] = (((b>>5)==r) && ((b&31)==l)) ? 1.f : 0.f;
    ai[r] = 0.f;
  }

  run_gates<0>(ar, ai, sgn, l, cv, sv);

  const int k  = b >> 5;
  const int qd = (b >> 3) & 3;
  const int jj = b & 7;
  #pragma unroll
  for (int r=0;r<8;r++){
    const int j   = r*32 + l;
    const int nt  = j >> 4;
    const int rr_ = j & 15;
    const size_t F = ((size_t)((nt*8 + k)*4 + qd)*16 + rr_)*8 + jj;
    Urf[F] = (_Float16)ar[r];
    Uif[F] = (_Float16)ai[r];
  }
}

// ================= Main kernel: persistent 4-tile loop, U register-resident ==============
// Per-iteration structure is byte-identical to the R6-PASSING 16-token pipeline.
#define PSTRIDE 272   // halfs: 544 B row stride
#define PFSTR   264   // floats: P row stride in the aliased Ts region
__global__ __launch_bounds__(512)
void qffb_main(const float* __restrict__ x,
               const _Float16* __restrict__ Urf,
               const _Float16* __restrict__ Uif,
               const float* __restrict__ W1,
               const float* __restrict__ b1,
               const float* __restrict__ W2,
               const float* __restrict__ b2,
               float* __restrict__ out)
{
  __shared__ _Float16 Ps[16*PSTRIDE];   // psi (f16)
  __shared__ _Float16 Hs[16][72];       // h tile (144 B stride, validated)
  __shared__ float    Ts[8][16*68];     // phase-4 epilogue; aliased as P (f32) before that
  float* Pf = &Ts[0][0];                // P[token][j], stride PFSTR (disjoint lifetime)

  const int tid  = threadIdx.x;
  const int lane = tid & 63;
  const int l    = lane & 31;
  const int wave = tid >> 6;
  const int rr   = lane & 15;
  const int quad = lane >> 4;
  const int trow = wave*2 + (lane>>5);          // 0..15

  // ---- hoisted: U B-fragments (register-resident across the tile loop) ----
  const size_t ub0 = ((size_t)((wave*2+0)*32 + quad)*16 + rr)*8;   // F(nt0,k=0,quad,rr,0)
  const size_t ub1 = ((size_t)((wave*2+1)*32 + quad)*16 + rr)*8;   // F(nt1,k=0,quad,rr,0)
  v8h Br0[8], Bi0[8], Br1[8], Bi1[8];
  #pragma unroll
  for (int k=0;k<8;++k){
    const size_t o = (size_t)k*512;               // k-step = 4*16*8 halfs
    Br0[k] = *(const v8h*)(Urf + ub0 + o);
    Bi0[k] = *(const v8h*)(Uif + ub0 + o);
    Br1[k] = *(const v8h*)(Urf + ub1 + o);
    Bi1[k] = *(const v8h*)(Uif + ub1 + o);
  }

  // ---- hoisted: sgn, W1 row pair, b1, W2 fragments, b2 ----
  float sgn[5];
  sgn[0] = (l&16) ? 1.f : -1.f;
  sgn[1] = (l& 8) ? 1.f : -1.f;
  sgn[2] = (l& 4) ? 1.f : -1.f;
  sgn[3] = (l& 2) ? 1.f : -1.f;
  sgn[4] = (l& 1) ? 1.f : -1.f;

  const float4 wA0 = *(const float4*)(W1 + (size_t)(2*l)*8);
  const float4 wA1 = *(const float4*)(W1 + (size_t)(2*l)*8 + 4);
  const float4 wB0 = *(const float4*)(W1 + (size_t)(2*l+1)*8);
  const float4 wB1 = *(const float4*)(W1 + (size_t)(2*l+1)*8 + 4);
  const float2 bb  = *(const float2*)(b1 + 2*l);

  const int ng = wave;
  v8h WB0[4], WB1[4];
  #pragma unroll
  for (int j=0;j<4;++j){
    const int e = ng*64 + j*16 + rr;
    const float4 wa = *(const float4*)(W2 + (size_t)e*64 + quad*8);
    const float4 wb = *(const float4*)(W2 + (size_t)e*64 + quad*8 + 4);
    const float4 wc = *(const float4*)(W2 + (size_t)e*64 + 32 + quad*8);
    const float4 wd = *(const float4*)(W2 + (size_t)e*64 + 32 + quad*8 + 4);
    WB0[j] = v8h{(_Float16)wa.x,(_Float16)wa.y,(_Float16)wa.z,(_Float16)wa.w,
                 (_Float16)wb.x,(_Float16)wb.y,(_Float16)wb.z,(_Float16)wb.w};
    WB1[j] = v8h{(_Float16)wc.x,(_Float16)wc.y,(_Float16)wc.z,(_Float16)wc.w,
                 (_Float16)wd.x,(_Float16)wd.y,(_Float16)wd.z,(_Float16)wd.w};
  }
  const float4 bias = *(const float4*)(b2 + ng*64 + rr*4);

  // ================= persistent loop over token tiles =================
  for (int it=0; it<TPB_TILES; ++it){
    const int tileIdx = blockIdx.x*TPB_TILES + it;
    const int token   = tileIdx*16 + trow;

    // ---- phase 1: product state psi (f16); lane l owns amps l*8..l*8+7 ----
    {
      const float4 xa = *(const float4*)(x + (size_t)token*E_DIM);
      const float4 xb = *(const float4*)(x + (size_t)token*E_DIM + 4);
      float c[8], s[8];
      float xs[8] = {xa.x, xa.y, xa.z, xa.w, xb.x, xb.y, xb.z, xb.w};
      #pragma unroll
      for (int w=0; w<8; ++w) __sincosf(0.5f*xs[w], &s[w], &c[w]);
      float L = ((l&16)? s[0]:c[0]) * ((l&8)? s[1]:c[1]);
      L *= ((l&4)? s[2]:c[2]) * ((l&2)? s[3]:c[3]);
      L *= ((l&1)? s[4]:c[4]);
      const float p67[4] = {c[6]*c[7], c[6]*s[7], s[6]*c[7], s[6]*s[7]};
      v8h v;
      #pragma unroll
      for (int i=0;i<8;++i)
        v[i] = (_Float16)(L * (((i&4)? s[5]:c[5]) * p67[i&3]));
      *(v8h*)&Ps[trow*PSTRIDE + l*8] = v;
    }
    __syncthreads();

    // ---- phase 2: S = psi @ U^T (K=256), B from registers ----
    v4f accr[2], acci[2];
    #pragma unroll
    for (int n=0;n<2;++n){ accr[n]=v4f{0.f,0.f,0.f,0.f}; acci[n]=v4f{0.f,0.f,0.f,0.f}; }

    #pragma unroll
    for (int k=0;k<8;++k){
      const v8h a0 = *(const v8h*)&Ps[rr*PSTRIDE + k*32 + quad*8];
      accr[0] = __builtin_amdgcn_mfma_f32_16x16x32_f16(a0, Br0[k], accr[0], 0,0,0);
      acci[0] = __builtin_amdgcn_mfma_f32_16x16x32_f16(a0, Bi0[k], acci[0], 0,0,0);
      accr[1] = __builtin_amdgcn_mfma_f32_16x16x32_f16(a0, Br1[k], accr[1], 0,0,0);
      acci[1] = __builtin_amdgcn_mfma_f32_16x16x32_f16(a0, Bi1[k], acci[1], 0,0,0);
    }

    // P store (f32). D layout (validated): row(token)=quad*4+r2, col(j-in-tile)=rr
    #pragma unroll
    for (int n=0;n<2;++n){
      const int nt = wave*2 + n;
      #pragma unroll
      for (int r2=0;r2<4;++r2)
        Pf[(quad*4+r2)*PFSTR + nt*16 + rr] =
            accr[n][r2]*accr[n][r2] + acci[n][r2]*acci[n][r2];
    }
    __syncthreads();

    // ---- phase 3: R6-validated e-reduce + W1 + relu + Hs store ----
    {
      float p[8];
      #pragma unroll
      for (int r=0;r<8;r++) p[r] = Pf[trow*PFSTR + r*32 + l];

      const float t1a=p[0]+p[1], t1b=p[2]+p[3], t1c=p[4]+p[5], t1d=p[6]+p[7];
      const float s0a=t1a+t1b, s0b=t1c+t1d;
      float P  = s0a + s0b;
      float e0 = s0a - s0b;
      float e1 = (t1a+t1c) - (t1b+t1d);
      float e2 = (p[0]-p[1])+(p[2]-p[3])+(p[4]-p[5])+(p[6]-p[7]);
      {
        float t;
        t=xl<1>(e0); e0+=t;  t=xl<1>(e1); e1+=t;  t=xl<1>(e2); e2+=t;
        t=xl<1>(P);  P = fmaf(-sgn[4], P, t);
        t=xl<2>(e0); e0+=t;  t=xl<2>(e1); e1+=t;  t=xl<2>(e2); e2+=t;
        t=xl<2>(P);  P = fmaf(-sgn[3], P, t);
        t=xl<4>(e0); e0+=t;  t=xl<4>(e1); e1+=t;  t=xl<4>(e2); e2+=t;
        t=xl<4>(P);  P = fmaf(-sgn[2], P, t);
        t=xl<8>(e0); e0+=t;  t=xl<8>(e1); e1+=t;  t=xl<8>(e2); e2+=t;
        t=xl<8>(P);  P = fmaf(-sgn[1], P, t);
        t=xl<16>(e0); e0+=t; t=xl<16>(e1); e1+=t; t=xl<16>(e2); e2+=t;
        t=xl<16>(P); P = fmaf(-sgn[0], P, t);
      }
      const float e3 = bcast<16>(P);
      const float e4 = bcast<8>(P);
      const float e5 = bcast<4>(P);
      const float e6 = bcast<2>(P);
      const float e7 = bcast<1>(P);

      float h0 = bb.x + wA0.x*e0 + wA0.y*e1 + wA0.z*e2 + wA0.w*e3
                      + wA1.x*e4 + wA1.y*e5 + wA1.z*e6 + wA1.w*e7;
      float h1 = bb.y + wB0.x*e0 + wB0.y*e1 + wB0.z*e2 + wB0.w*e3
                      + wB1.x*e4 + wB1.y*e5 + wB1.z*e6 + wB1.w*e7;
      HU pk;
      pk.h = v2h{(_Float16)fmaxf(h0,0.f), (_Float16)fmaxf(h1,0.f)};
      *(uint32_t*)((char*)&Hs[trow][0] + 4*l) = pk.u;
    }
    __syncthreads();   // Hs complete; all Pf reads done before Ts is overwritten below

    // ---- phase 4: R6-validated out = H @ W2^T + b2 (W2 frags from registers) ----
    {
      const v8h a0 = *(const v8h*)&Hs[rr][quad*8];
      const v8h a1 = *(const v8h*)&Hs[rr][32 + quad*8];

      #pragma unroll
      for (int j=0;j<4;++j){
        v4f acc = {0.f,0.f,0.f,0.f};
        acc = __builtin_amdgcn_mfma_f32_16x16x32_f16(a0, WB0[j], acc, 0, 0, 0);
        acc = __builtin_amdgcn_mfma_f32_16x16x32_f16(a1, WB1[j], acc, 0, 0, 0);
        #pragma unroll
        for (int r2=0;r2<4;r2++)
          Ts[wave][(quad*4+r2)*68 + j*16 + rr] = acc[r2];
      }

      // per-wave tile: same-wave LDS write->read is in-order (validated pattern)
      #pragma unroll
      for (int k=0;k<4;++k){
        const int row = 4*k + quad;
        float4 v = *(const float4*)&Ts[wave][row*68 + rr*4];
        v.x += bias.x; v.y += bias.y; v.z += bias.z; v.w += bias.w;
        const int t = tileIdx*16 + row;
        *(float4*)(out + (size_t)t*E_DIM + ng*64 + rr*4) = v;
      }
    }
    // no barrier needed here: next iteration's first LDS write to Pf/Ts happens only
    // after the post-phase-1 __syncthreads, by which point all waves finished phase 4.
  }
}

extern "C" void kernel_launch(void* const* d_in, const int* in_sizes, int n_in,
                              void* d_out, int out_size, void* d_ws, size_t ws_size,
                              hipStream_t stream)
{
  (void)n_in; (void)out_size; (void)ws_size;
  const int ntok = in_sizes[0] / E_DIM;            // 16384
  char* ws = (char*)d_ws;
  _Float16* Urf = (_Float16*)(ws);                 // 128 KB (fragment layout)
  _Float16* Uif = (_Float16*)(ws + 131072);        // 128 KB

  qffb_pre<<<16, 512, 0, stream>>>(
      (const float*)d_in[1],   // ry_theta
      (const float*)d_in[2],   // rand_params
      Urf, Uif);

  qffb_main<<<ntok/16/TPB_TILES, 512, 0, stream>>>(
      (const float*)d_in[0],   // x
      Urf, Uif,
      (const float*)d_in[3],   // W1
      (const float*)d_in[4],   // b1
      (const float*)d_in[5],   // W2
      (const float*)d_in[6],   // b2
      (float*)d_out);
}

// Round 8
// 109.139 us; speedup vs baseline: 1.3129x; 1.0013x over previous
//
#include <hip/hip_runtime.h>
#include <hip/hip_fp16.h>
#include <cstdint>

#define N_RAND   20
#define N_GATES  28
#define E_DIM    512
#define TPB_TILES 4   // token-tiles (16 tokens) per block

struct OpsArg { int d[N_GATES]; };

// ---------- compile-time replication of np.random.RandomState(0) op list ----------
struct MT19937ce {
  uint32_t mt[624] = {};
  int mti = 0;
  constexpr void seed(uint32_t s){
    mt[0]=s;
    for(int i=1;i<624;i++) mt[i]=1812433253u*(mt[i-1]^(mt[i-1]>>30))+(uint32_t)i;
    mti=624;
  }
  constexpr uint32_t next(){
    if(mti>=624){
      for(int i=0;i<624;i++){
        uint32_t y=(mt[i]&0x80000000u)|(mt[(i+1)%624]&0x7fffffffu);
        mt[i]=mt[(i+397)%624]^(y>>1)^((y&1u)?0x9908b0dfu:0u);
      }
      mti=0;
    }
    uint32_t y=mt[mti++];
    y^=y>>11; y^=(y<<7)&0x9d2c5680u; y^=(y<<15)&0xefc60000u; y^=y>>18;
    return y;
  }
  constexpr uint32_t interval(uint32_t mx){
    if(!mx) return 0;
    uint32_t mask=mx; mask|=mask>>1; mask|=mask>>2; mask|=mask>>4; mask|=mask>>8; mask|=mask>>16;
    uint32_t v = next()&mask;
    while(v>mx) v = next()&mask;
    return v;
  }
};

constexpr OpsArg build_ops_ce(){
  MT19937ce rs; rs.seed(0);
  OpsArg o{};
  for(int i=0;i<N_RAND;i++){
    uint32_t k = rs.interval(3);
    if(k==3){
      int perm[8] = {0,1,2,3,4,5,6,7};
      for(int j=7;j>=1;j--){
        uint32_t t=rs.interval((uint32_t)j);
        int tmp=perm[j]; perm[j]=perm[t]; perm[t]=tmp;
      }
      o.d[i] = 3 | (perm[0]<<2) | (perm[1]<<5);
    } else {
      uint32_t w = rs.interval(7);
      o.d[i] = (int)k | ((int)w<<2);
    }
  }
  for(int i=0;i<8;i++) o.d[N_RAND+i] = 1 | (i<<2);
  return o;
}
inline constexpr OpsArg OPS = build_ops_ce();

// ---------- device helpers ----------
__device__ __forceinline__ float readlane_f(float v, int l){
  return __int_as_float(__builtin_amdgcn_readlane(__float_as_int(v), l));
}
template<int CTRL>
__device__ __forceinline__ float dpp_mov(float v){
  int s = __float_as_int(v);
  return __int_as_float(__builtin_amdgcn_update_dpp(s, s, CTRL, 0xF, 0xF, false));
}
// cross-lane xor<M> within 32-lane groups (M in {1,2,4,8,16})
template<int M>
__device__ __forceinline__ float xl(float v){
  if constexpr (M==1)      return dpp_mov<0xB1>(v);            // quad_perm [1,0,3,2]
  else if constexpr (M==2) return dpp_mov<0x4E>(v);            // quad_perm [2,3,0,1]
  else return __int_as_float(__builtin_amdgcn_ds_swizzle(__float_as_int(v), (M<<10)|0x1F));
}

typedef _Float16 v2h __attribute__((ext_vector_type(2)));
typedef _Float16 v8h __attribute__((ext_vector_type(8)));
typedef float    v4f __attribute__((ext_vector_type(4)));

// ---------- fully specialized gate chain (amp idx = r*32 + l, standard bit order) ----------
template<int G>
__device__ __forceinline__ void run_gates(float (&ar)[8], float (&ai)[8],
                                          const float (&sgn)[5], int l,
                                          float cv, float sv)
{
  if constexpr (G < N_GATES){
    constexpr int dd   = OPS.d[G];
    constexpr int kind = dd & 3;
    constexpr int wa   = (dd>>2) & 7;
    constexpr int wb   = (dd>>5) & 7;
    const float gc = readlane_f(cv, G);
    const float gs = readlane_f(sv, G);

    if constexpr (kind == 3){                       // ---- CNOT c=wa t=wb ----
      if constexpr (wa < 3 && wb < 3){
        constexpr int Rc = 4>>wa, Rt = 4>>wb;
        #pragma unroll
        for (int r=0;r<8;r++){
          if ((r & Rc) && !(r & Rt)){
            float t0=ar[r]; ar[r]=ar[r|Rt]; ar[r|Rt]=t0;
            float t1=ai[r]; ai[r]=ai[r|Rt]; ai[r|Rt]=t1;
          }
        }
      } else if constexpr (wa < 3){
        constexpr int Rc = 4>>wa, Mt = 16>>(wb-3);
        #pragma unroll
        for (int r=0;r<8;r++){
          if (r & Rc){ ar[r]=xl<Mt>(ar[r]); ai[r]=xl<Mt>(ai[r]); }
        }
      } else if constexpr (wb < 3){
        constexpr int Mc = 16>>(wa-3), Rt = 4>>wb;
        const bool cb = (l & Mc) != 0;
        #pragma unroll
        for (int r=0;r<8;r++){
          if (!(r & Rt)){
            float alo=ar[r], ahi=ar[r|Rt];
            ar[r]    = cb ? ahi : alo;  ar[r|Rt] = cb ? alo : ahi;
            float blo=ai[r], bhi=ai[r|Rt];
            ai[r]    = cb ? bhi : blo;  ai[r|Rt] = cb ? blo : bhi;
          }
        }
      } else {
        constexpr int Mc = 16>>(wa-3), Mt = 16>>(wb-3);
        const bool cb = (l & Mc) != 0;
        #pragma unroll
        for (int r=0;r<8;r++){
          float pr = xl<Mt>(ar[r]), pi_ = xl<Mt>(ai[r]);
          ar[r] = cb ? pr  : ar[r];
          ai[r] = cb ? pi_ : ai[r];
        }
      }
    } else if constexpr (kind == 2){                // ---- RZ wa ----
      if constexpr (wa < 3){
        constexpr int Rb = 4>>wa;
        #pragma unroll
        for (int r=0;r<8;r++){
          const float pim = (r & Rb) ? gs : -gs;
          float nr = gc*ar[r] - pim*ai[r];
          ai[r] = gc*ai[r] + pim*ar[r];
          ar[r] = nr;
        }
      } else {
        constexpr int SI = wa-3;
        const float pim = sgn[SI]*gs;
        #pragma unroll
        for (int r=0;r<8;r++){
          float nr = gc*ar[r] - pim*ai[r];
          ai[r] = gc*ai[r] + pim*ar[r];
          ar[r] = nr;
        }
      }
    } else if constexpr (kind == 1){                // ---- RY wa ----
      if constexpr (wa < 3){
        constexpr int Rb = 4>>wa;
        #pragma unroll
        for (int r=0;r<8;r++){
          if (!(r & Rb)){
            const int h = r|Rb;
            float lr=ar[r], li=ai[r], hr=ar[h], hii=ai[h];
            ar[r]=gc*lr - gs*hr;  ai[r]=gc*li - gs*hii;
            ar[h]=gs*lr + gc*hr;  ai[h]=gs*li + gc*hii;
          }
        }
      } else {
        constexpr int M = 16>>(wa-3), SI = wa-3;
        const float sg = sgn[SI]*gs;
        #pragma unroll
        for (int r=0;r<8;r++){
          float pr = xl<M>(ar[r]), pi_ = xl<M>(ai[r]);
          ar[r] = gc*ar[r] + sg*pr;
          ai[r] = gc*ai[r] + sg*pi_;
        }
      }
    } else {                                        // ---- RX wa ----
      if constexpr (wa < 3){
        constexpr int Rb = 4>>wa;
        #pragma unroll
        for (int r=0;r<8;r++){
          if (!(r & Rb)){
            const int h = r|Rb;
            float lr=ar[r], li=ai[r], hr=ar[h], hii=ai[h];
            ar[r]=gc*lr + gs*hii;  ai[r]=gc*li - gs*hr;
            ar[h]=gc*hr + gs*li;   ai[h]=gc*hii - gs*lr;
          }
        }
      } else {
        constexpr int M = 16>>(wa-3);
        #pragma unroll
        for (int r=0;r<8;r++){
          float pr = xl<M>(ar[r]), pi_ = xl<M>(ai[r]);
          ar[r] = gc*ar[r] + gs*pi_;
          ai[r] = gc*ai[r] - gs*pr;
        }
      }
    }
    run_gates<G+1>(ar, ai, sgn, l, cv, sv);
  }
}

// ================= Pre-kernel: build U columns, store in MFMA-FRAGMENT order ==============
// Fragment layout: F(nt,k,quad,rr,jj) = (((nt*8 + k)*4 + quad)*16 + rr)*8 + jj
// nt = j>>4, rr = j&15 (j = row of U); k = b>>5, quad = (b>>3)&3, jj = b&7 (b = col).
__global__ __launch_bounds__(512)
void qffb_pre(const float* __restrict__ ry_theta,
              const float* __restrict__ rand_params,
              _Float16* __restrict__ Urf,
              _Float16* __restrict__ Uif)
{
  const int tid  = threadIdx.x;
  const int lane = tid & 63;
  const int l    = lane & 31;
  const int wave = tid >> 6;
  const int b    = blockIdx.x*16 + wave*2 + (lane>>5);   // basis (column) index 0..255

  float th = 0.f;
  if (lane < N_GATES)
    th = (lane < N_RAND) ? rand_params[lane] : ry_theta[lane - N_RAND];
  float cv, sv;
  __sincosf(0.5f*th, &sv, &cv);

  float sgn[5];
  sgn[0] = (l&16) ? 1.f : -1.f;
  sgn[1] = (l& 8) ? 1.f : -1.f;
  sgn[2] = (l& 4) ? 1.f : -1.f;
  sgn[3] = (l& 2) ? 1.f : -1.f;
  sgn[4] = (l& 1) ? 1.f : -1.f;

  float ar[8], ai[8];
  #pragma unroll
  for (int r=0;r<8;r++){
    ar[r] = (((b>>5)==r) && ((b&31)==l)) ? 1.f : 0.f;
    ai[r] = 0.f;
  }

  run_gates<0>(ar, ai, sgn, l, cv, sv);

  const int k  = b >> 5;
  const int qd = (b >> 3) & 3;
  const int jj = b & 7;
  #pragma unroll
  for (int r=0;r<8;r++){
    const int j   = r*32 + l;
    const int nt  = j >> 4;
    const int rr_ = j & 15;
    const size_t F = ((size_t)((nt*8 + k)*4 + qd)*16 + rr_)*8 + jj;
    Urf[F] = (_Float16)ar[r];
    Uif[F] = (_Float16)ai[r];
  }
}

// ================= Main kernel: persistent 4-tile loop, U register-resident ==============
// Per-iteration: P1 psi -> P2 S-GEMM + |.|^2 (f16 P) -> P3' h = P @ W1Z^T via MFMA -> P4 W2.
#define PSTRIDE 272   // halfs: psi row stride (544 B)
#define PQSTR   264   // halfs: P row stride (528 B) — same bank pattern as validated Hs[16][72]
__global__ __launch_bounds__(512)
void qffb_main(const float* __restrict__ x,
               const _Float16* __restrict__ Urf,
               const _Float16* __restrict__ Uif,
               const float* __restrict__ W1,
               const float* __restrict__ b1,
               const float* __restrict__ W2,
               const float* __restrict__ b2,
               float* __restrict__ out)
{
  __shared__ _Float16 Ps[16*PSTRIDE];   // psi (f16)
  __shared__ _Float16 Pq[16*PQSTR];     // P = |S|^2 (f16, MFMA-A layout)
  __shared__ _Float16 Hs[16][72];       // h tile (144 B stride, validated)
  __shared__ float    Ts[8][16*68];     // phase-4 epilogue (per-wave)

  const int tid  = threadIdx.x;
  const int lane = tid & 63;
  const int l    = lane & 31;
  const int wave = tid >> 6;
  const int rr   = lane & 15;
  const int quad = lane >> 4;
  const int trow = wave*2 + (lane>>5);          // 0..15

  // ---- hoisted: U B-fragments (register-resident across the tile loop) ----
  const size_t ub0 = ((size_t)((wave*2+0)*32 + quad)*16 + rr)*8;   // F(nt0,k=0,quad,rr,0)
  const size_t ub1 = ((size_t)((wave*2+1)*32 + quad)*16 + rr)*8;   // F(nt1,k=0,quad,rr,0)
  v8h Br0[8], Bi0[8], Br1[8], Bi1[8];
  #pragma unroll
  for (int k=0;k<8;++k){
    const size_t o = (size_t)k*512;               // k-step = 4*16*8 halfs
    Br0[k] = *(const v8h*)(Urf + ub0 + o);
    Bi0[k] = *(const v8h*)(Uif + ub0 + o);
    Br1[k] = *(const v8h*)(Urf + ub1 + o);
    Bi1[k] = *(const v8h*)(Uif + ub1 + o);
  }

  // ---- hoisted: in-register W1Z fragments (waves 0..3 only) ----
  // h[o] = sum_j P[j]*W1Z[o][j], W1Z[o][j] = sum_w W1[o][w]*(1-2*((j>>(7-w))&1)).
  // B-frag for n-tile = wave: lane (rr,quad), elem jj, k-step k -> j = k*32+quad*8+jj.
  // j bits: [7:5]=k (wires 0-2), [4:3]=quad (wires 3-4), [2:0]=jj (wires 5-7).
  v8h WZ[8];
  float b1o = 0.f;
  if (wave < 4){
    const int o = wave*16 + rr;
    const float4 w1a = *(const float4*)(W1 + (size_t)o*8);      // W1[o][0..3]
    const float4 w1b = *(const float4*)(W1 + (size_t)o*8 + 4);  // W1[o][4..7]
    b1o = b1[o];
    const float q = ((quad&2)? -w1a.w : w1a.w) + ((quad&1)? -w1b.x : w1b.x);
    float sk[8], sj[8];
    #pragma unroll
    for (int k=0;k<8;++k)
      sk[k] = ((k&4)? -w1a.x : w1a.x) + ((k&2)? -w1a.y : w1a.y) + ((k&1)? -w1a.z : w1a.z);
    #pragma unroll
    for (int jj=0;jj<8;++jj)
      sj[jj] = ((jj&4)? -w1b.y : w1b.y) + ((jj&2)? -w1b.z : w1b.z) + ((jj&1)? -w1b.w : w1b.w);
    #pragma unroll
    for (int k=0;k<8;++k){
      v8h t;
      #pragma unroll
      for (int jj=0;jj<8;++jj) t[jj] = (_Float16)(sk[k] + q + sj[jj]);
      WZ[k] = t;
    }
  }

  // ---- hoisted: W2 fragments, b2 ----
  const int ng = wave;
  v8h WB0[4], WB1[4];
  #pragma unroll
  for (int j=0;j<4;++j){
    const int e = ng*64 + j*16 + rr;
    const float4 wa = *(const float4*)(W2 + (size_t)e*64 + quad*8);
    const float4 wb = *(const float4*)(W2 + (size_t)e*64 + quad*8 + 4);
    const float4 wc = *(const float4*)(W2 + (size_t)e*64 + 32 + quad*8);
    const float4 wd = *(const float4*)(W2 + (size_t)e*64 + 32 + quad*8 + 4);
    WB0[j] = v8h{(_Float16)wa.x,(_Float16)wa.y,(_Float16)wa.z,(_Float16)wa.w,
                 (_Float16)wb.x,(_Float16)wb.y,(_Float16)wb.z,(_Float16)wb.w};
    WB1[j] = v8h{(_Float16)wc.x,(_Float16)wc.y,(_Float16)wc.z,(_Float16)wc.w,
                 (_Float16)wd.x,(_Float16)wd.y,(_Float16)wd.z,(_Float16)wd.w};
  }
  const float4 bias = *(const float4*)(b2 + ng*64 + rr*4);

  // ================= persistent loop over token tiles =================
  for (int it=0; it<TPB_TILES; ++it){
    const int tileIdx = blockIdx.x*TPB_TILES + it;
    const int token   = tileIdx*16 + trow;

    // ---- phase 1: product state psi (f16); lane l owns amps l*8..l*8+7 ----
    {
      const float4 xa = *(const float4*)(x + (size_t)token*E_DIM);
      const float4 xb = *(const float4*)(x + (size_t)token*E_DIM + 4);
      float c[8], s[8];
      float xs[8] = {xa.x, xa.y, xa.z, xa.w, xb.x, xb.y, xb.z, xb.w};
      #pragma unroll
      for (int w=0; w<8; ++w) __sincosf(0.5f*xs[w], &s[w], &c[w]);
      float L = ((l&16)? s[0]:c[0]) * ((l&8)? s[1]:c[1]);
      L *= ((l&4)? s[2]:c[2]) * ((l&2)? s[3]:c[3]);
      L *= ((l&1)? s[4]:c[4]);
      const float p67[4] = {c[6]*c[7], c[6]*s[7], s[6]*c[7], s[6]*s[7]};
      v8h v;
      #pragma unroll
      for (int i=0;i<8;++i)
        v[i] = (_Float16)(L * (((i&4)? s[5]:c[5]) * p67[i&3]));
      *(v8h*)&Ps[trow*PSTRIDE + l*8] = v;
    }
    __syncthreads();

    // ---- phase 2: S = psi @ U^T (K=256), B from registers; P -> Pq (f16) ----
    v4f accr[2], acci[2];
    #pragma unroll
    for (int n=0;n<2;++n){ accr[n]=v4f{0.f,0.f,0.f,0.f}; acci[n]=v4f{0.f,0.f,0.f,0.f}; }

    #pragma unroll
    for (int k=0;k<8;++k){
      const v8h a0 = *(const v8h*)&Ps[rr*PSTRIDE + k*32 + quad*8];
      accr[0] = __builtin_amdgcn_mfma_f32_16x16x32_f16(a0, Br0[k], accr[0], 0,0,0);
      acci[0] = __builtin_amdgcn_mfma_f32_16x16x32_f16(a0, Bi0[k], acci[0], 0,0,0);
      accr[1] = __builtin_amdgcn_mfma_f32_16x16x32_f16(a0, Br1[k], accr[1], 0,0,0);
      acci[1] = __builtin_amdgcn_mfma_f32_16x16x32_f16(a0, Bi1[k], acci[1], 0,0,0);
    }

    // P store (f16). D layout (validated): row(token)=quad*4+r2, col(j)=nt*16+rr
    #pragma unroll
    for (int n=0;n<2;++n){
      const int nt = wave*2 + n;
      #pragma unroll
      for (int r2=0;r2<4;++r2){
        const float pv = accr[n][r2]*accr[n][r2] + acci[n][r2]*acci[n][r2];
        Pq[(quad*4+r2)*PQSTR + nt*16 + rr] = (_Float16)pv;
      }
    }
    __syncthreads();

    // ---- phase 3': h = relu(P @ W1Z^T + b1) via MFMA (waves 0..3, n-tile = wave) ----
    if (wave < 4){
      v4f acc = {0.f,0.f,0.f,0.f};
      #pragma unroll
      for (int k=0;k<8;++k){
        const v8h a = *(const v8h*)&Pq[rr*PQSTR + k*32 + quad*8];
        acc = __builtin_amdgcn_mfma_f32_16x16x32_f16(a, WZ[k], acc, 0,0,0);
      }
      // D: row(token)=quad*4+r2, col(o-in-tile)=rr -> Hs[token][wave*16+rr]
      #pragma unroll
      for (int r2=0;r2<4;++r2){
        const float h = fmaxf(acc[r2] + b1o, 0.f);
        Hs[quad*4+r2][wave*16 + rr] = (_Float16)h;
      }
    }
    __syncthreads();   // Hs complete

    // ---- phase 4: R7-validated out = H @ W2^T + b2 (W2 frags from registers) ----
    {
      const v8h a0 = *(const v8h*)&Hs[rr][quad*8];
      const v8h a1 = *(const v8h*)&Hs[rr][32 + quad*8];

      #pragma unroll
      for (int j=0;j<4;++j){
        v4f acc = {0.f,0.f,0.f,0.f};
        acc = __builtin_amdgcn_mfma_f32_16x16x32_f16(a0, WB0[j], acc, 0, 0, 0);
        acc = __builtin_amdgcn_mfma_f32_16x16x32_f16(a1, WB1[j], acc, 0, 0, 0);
        #pragma unroll
        for (int r2=0;r2<4;r2++)
          Ts[wave][(quad*4+r2)*68 + j*16 + rr] = acc[r2];
      }

      // per-wave tile: same-wave LDS write->read is in-order (validated pattern)
      #pragma unroll
      for (int k=0;k<4;++k){
        const int row = 4*k + quad;
        float4 v = *(const float4*)&Ts[wave][row*68 + rr*4];
        v.x += bias.x; v.y += bias.y; v.z += bias.z; v.w += bias.w;
        const int t = tileIdx*16 + row;
        *(float4*)(out + (size_t)t*E_DIM + ng*64 + rr*4) = v;
      }
    }
    // no loop-end barrier needed: next iteration's LDS writes (Ps in P1, Pq in P2)
    // are separated from this iteration's reads by the P1->P2 barrier (Ps argument
    // identical to R7; Pq reads in P3' precede the P3'->P4 barrier).
  }
}

extern "C" void kernel_launch(void* const* d_in, const int* in_sizes, int n_in,
                              void* d_out, int out_size, void* d_ws, size_t ws_size,
                              hipStream_t stream)
{
  (void)n_in; (void)out_size; (void)ws_size;
  const int ntok = in_sizes[0] / E_DIM;            // 16384
  char* ws = (char*)d_ws;
  _Float16* Urf = (_Float16*)(ws);                 // 128 KB (fragment layout)
  _Float16* Uif = (_Float16*)(ws + 131072);        // 128 KB

  qffb_pre<<<16, 512, 0, stream>>>(
      (const float*)d_in[1],   // ry_theta
      (const float*)d_in[2],   // rand_params
      Urf, Uif);

  qffb_main<<<ntok/16/TPB_TILES, 512, 0, stream>>>(
      (const float*)d_in[0],   // x
      Urf, Uif,
      (const float*)d_in[3],   // W1
      (const float*)d_in[4],   // b1
      (const float*)d_in[5],   // W2
      (const float*)d_in[6],   // b2
      (float*)d_out);
}